// Round 3
// baseline (310.157 us; speedup 1.0000x reference)
//
#include <hip/hip_runtime.h>
#include <hip/hip_bf16.h>
#include <cstdint>

using bf16 = __hip_bfloat16;
typedef __attribute__((ext_vector_type(8))) __bf16 bf16x8;
typedef __attribute__((ext_vector_type(4))) float f32x4;

#define MFMA16(a, b, c) __builtin_amdgcn_mfma_f32_16x16x32_bf16((a), (b), (c), 0, 0, 0)

#if __has_builtin(__builtin_amdgcn_exp2f)
__device__ __forceinline__ float fexp2(float x) { return __builtin_amdgcn_exp2f(x); }
#else
__device__ __forceinline__ float fexp2(float x) { return exp2f(x); }
#endif

// Async global->LDS 16B copy. LDS dest must be wave-uniform base + lane*16.
__device__ __forceinline__ void async16(void* lds_ptr, const void* gptr) {
  auto g = reinterpret_cast<__attribute__((address_space(1))) unsigned int*>(
      reinterpret_cast<uintptr_t>(gptr));
  auto l = reinterpret_cast<__attribute__((address_space(3))) unsigned int*>(
      static_cast<unsigned int>(reinterpret_cast<uintptr_t>(lds_ptr)));
  __builtin_amdgcn_global_load_lds(g, l, 16, 0, 0);
}

// ---------------------------------------------------------------- RMSNorm ----
__global__ __launch_bounds__(256) void rmsnorm_cast_k(
    const float* __restrict__ x, const float* __restrict__ sc, bf16* __restrict__ xn) {
  const int row = blockIdx.x, tid = threadIdx.x;
  const float4* xr = (const float4*)(x + (size_t)row * 2048);
  float4 a = xr[tid * 2], b = xr[tid * 2 + 1];
  float ss = a.x * a.x + a.y * a.y + a.z * a.z + a.w * a.w +
             b.x * b.x + b.y * b.y + b.z * b.z + b.w * b.w;
#pragma unroll
  for (int d = 1; d < 64; d <<= 1) ss += __shfl_xor(ss, d);
  __shared__ float sm[4];
  if ((tid & 63) == 0) sm[tid >> 6] = ss;
  __syncthreads();
  const float rinv = rsqrtf((sm[0] + sm[1] + sm[2] + sm[3]) * (1.0f / 2048.0f) + 1e-6f);
  const float4* sp = (const float4*)sc;
  float4 s0 = sp[tid * 2], s1 = sp[tid * 2 + 1];
  union { bf16 h[8]; bf16x8 v; } o;
  o.h[0] = __float2bfloat16(a.x * rinv * s0.x);
  o.h[1] = __float2bfloat16(a.y * rinv * s0.y);
  o.h[2] = __float2bfloat16(a.z * rinv * s0.z);
  o.h[3] = __float2bfloat16(a.w * rinv * s0.w);
  o.h[4] = __float2bfloat16(b.x * rinv * s1.x);
  o.h[5] = __float2bfloat16(b.y * rinv * s1.y);
  o.h[6] = __float2bfloat16(b.z * rinv * s1.z);
  o.h[7] = __float2bfloat16(b.w * rinv * s1.w);
  *(bf16x8*)(xn + (size_t)row * 2048 + tid * 8) = o.v;
}

// ------------------------------------------------- weight transpose + cast ----
__global__ void transpose_cast_k(const float* __restrict__ W, bf16* __restrict__ Wt,
                                 int N, int row_off) {
  __shared__ float t[32][33];
  const int n0 = blockIdx.x * 32, k0 = blockIdx.y * 32;
  const int tx = threadIdx.x, ty = threadIdx.y;
#pragma unroll
  for (int i = 0; i < 4; ++i)
    t[ty + 8 * i][tx] = W[(size_t)(k0 + ty + 8 * i) * N + n0 + tx];
  __syncthreads();
#pragma unroll
  for (int i = 0; i < 4; ++i)
    Wt[(size_t)(row_off + n0 + ty + 8 * i) * 2048 + k0 + tx] =
        __float2bfloat16(t[tx][ty + 8 * i]);
}

// V slice of QKV [4096][3072] (cols 2560..3071) -> Vt bf16 [16][128][1024]
__global__ void transpose_v_k(const bf16* __restrict__ qkv, bf16* __restrict__ vtb) {
  __shared__ bf16 t[32][33];
  const int bh = blockIdx.z, b = bh >> 2, g = bh & 3;
  const int s0 = blockIdx.x * 32, d0 = blockIdx.y * 32;
  const int tx = threadIdx.x, ty = threadIdx.y;
#pragma unroll
  for (int i = 0; i < 4; ++i)
    t[ty + 8 * i][tx] =
        qkv[(size_t)(b * 1024 + s0 + ty + 8 * i) * 3072 + 2560 + g * 128 + d0 + tx];
  __syncthreads();
#pragma unroll
  for (int i = 0; i < 4; ++i)
    vtb[((size_t)bh * 128 + d0 + ty + 8 * i) * 1024 + s0 + tx] = t[tx][ty + 8 * i];
}

__global__ void concat_bias_k(const float* __restrict__ bq, const float* __restrict__ bk,
                              const float* __restrict__ bv, const float* __restrict__ b1,
                              float* __restrict__ o) {
  const int i = blockIdx.x * 256 + threadIdx.x;
  if (i < 2048) o[i] = bq[i];
  else if (i < 2560) o[i] = bk[i - 2048];
  else if (i < 3072) o[i] = bv[i - 2560];
  else o[i] = b1[i - 3072];
}

// ------------------------------------------------------- pipelined GEMM ------
// C[M][N] = A[M][K] @ Bt[N][K]^T. Tile 256x128, BK=64, 512 thr (8 waves, 4Mx2N).
// 2 phases per K-tile, counted vmcnt(6), LDS XOR-swizzle, setprio around MFMA.
// EPI 0: merged QKV+W1 (bcol<3072 -> bf16 out0 ld 3072; else silu-sq -> bf16
// out1 ld 2048). EPI 1: f32 out0 = acc + bias + res, ld 2048.
__device__ __forceinline__ void stage_tile(const bf16* __restrict__ A,
                                           const bf16* __restrict__ Bt,
                                           unsigned char* As, unsigned char* Bs,
                                           int tid, int brow, int bcol, int K, int k0) {
#pragma unroll
  for (int c = 0; c < 4; ++c) {
    const int o = c * 8192 + tid * 16;
    const int row = o >> 7;
    const int col = ((o & 127) ^ ((row & 7) << 4)) >> 1;
    async16(As + o, A + (size_t)(brow + row) * K + k0 + col);
  }
#pragma unroll
  for (int c = 0; c < 2; ++c) {
    const int o = c * 8192 + tid * 16;
    const int row = o >> 7;
    const int col = ((o & 127) ^ ((row & 7) << 4)) >> 1;
    async16(Bs + o, Bt + (size_t)(bcol + row) * K + k0 + col);
  }
}

template <int EPI>
__global__ __launch_bounds__(512, 2) void gemm_p(
    const bf16* __restrict__ A, const bf16* __restrict__ Bt,
    const float* __restrict__ bias, const float* __restrict__ res,
    void* __restrict__ out0, void* __restrict__ out1, int K) {
  __shared__ __align__(16) unsigned char lds[98304];  // A: 2x32KB, B: 2x16KB
  const int tid = threadIdx.x, lane = tid & 63, w = tid >> 6;
  const int wr = w >> 1, wc = w & 1;
  const int hi = lane >> 4, lo = lane & 15;
  const int brow = blockIdx.x * 256, bcol = blockIdx.y * 128;
  const int nt = K >> 6;

  stage_tile(A, Bt, lds, lds + 65536, tid, brow, bcol, K, 0);
  stage_tile(A, Bt, lds + 32768, lds + 81920, tid, brow, bcol, K, 64);
  asm volatile("s_waitcnt vmcnt(6)" ::: "memory");
  __builtin_amdgcn_s_barrier();
  asm volatile("" ::: "memory");

  f32x4 acc[4][4] = {};

  for (int t = 0; t < nt; ++t) {
    unsigned char* As = lds + (t & 1) * 32768;
    unsigned char* Bs = lds + 65536 + (t & 1) * 16384;
    // ---- phase 1: all frag reads, then MFMA quadrant nj0-1 ----
    bf16x8 af[4][2], bfr[4][2];
#pragma unroll
    for (int mi = 0; mi < 4; ++mi) {
      const int R = wr * 64 + mi * 16 + lo;
#pragma unroll
      for (int kk = 0; kk < 2; ++kk)
        af[mi][kk] = *(const bf16x8*)(As + R * 128 + ((kk * 64 + hi * 16) ^ ((R & 7) << 4)));
    }
#pragma unroll
    for (int nj = 0; nj < 4; ++nj) {
      const int S = wc * 64 + nj * 16 + lo;
#pragma unroll
      for (int kk = 0; kk < 2; ++kk)
        bfr[nj][kk] = *(const bf16x8*)(Bs + S * 128 + ((kk * 64 + hi * 16) ^ ((S & 7) << 4)));
    }
    asm volatile("" ::: "memory");
    __builtin_amdgcn_s_barrier();
    __builtin_amdgcn_s_setprio(1);
#pragma unroll
    for (int mi = 0; mi < 4; ++mi)
#pragma unroll
      for (int nj = 0; nj < 2; ++nj)
#pragma unroll
        for (int kk = 0; kk < 2; ++kk)
          acc[mi][nj] = MFMA16(af[mi][kk], bfr[nj][kk], acc[mi][nj]);
    __builtin_amdgcn_s_setprio(0);
    // all LDS reads of this buffer serviced before any wave may overwrite it
    asm volatile("s_waitcnt lgkmcnt(0)" ::: "memory");
    __builtin_amdgcn_s_barrier();
    asm volatile("" ::: "memory");
    // ---- phase 2: stage t+2 into this buffer, counted vmcnt, MFMA nj2-3 ----
    if (t + 2 < nt) {
      stage_tile(A, Bt, As, Bs, tid, brow, bcol, K, (t + 2) * 64);
      asm volatile("s_waitcnt vmcnt(6)" ::: "memory");
    } else {
      asm volatile("s_waitcnt vmcnt(0)" ::: "memory");
    }
    __builtin_amdgcn_s_barrier();
    __builtin_amdgcn_s_setprio(1);
#pragma unroll
    for (int mi = 0; mi < 4; ++mi)
#pragma unroll
      for (int nj = 2; nj < 4; ++nj)
#pragma unroll
        for (int kk = 0; kk < 2; ++kk)
          acc[mi][nj] = MFMA16(af[mi][kk], bfr[nj][kk], acc[mi][nj]);
    __builtin_amdgcn_s_setprio(0);
    asm volatile("" ::: "memory");
    __builtin_amdgcn_s_barrier();
    asm volatile("" ::: "memory");
  }

#pragma unroll
  for (int nj = 0; nj < 4; ++nj) {
    const int col = bcol + wc * 64 + nj * 16 + lo;
#pragma unroll
    for (int mi = 0; mi < 4; ++mi) {
      const int row0 = brow + wr * 64 + mi * 16 + hi * 4;
#pragma unroll
      for (int r = 0; r < 4; ++r) {
        float v = acc[mi][nj][r] + bias[col];
        const int row = row0 + r;
        if (EPI == 0) {
          if (bcol < 3072) {
            ((bf16*)out0)[(size_t)row * 3072 + col] = __float2bfloat16(v);
          } else {
            const float sg = 1.0f / (1.0f + __expf(-v));
            v = v * sg * v;
            ((bf16*)out1)[(size_t)row * 2048 + (col - 3072)] = __float2bfloat16(v);
          }
        } else {
          v += res[(size_t)row * 2048 + col];
          ((float*)out0)[(size_t)row * 2048 + col] = v;
        }
      }
    }
  }
}

// --------------------------------------------------------------- attention ----
__global__ __launch_bounds__(256, 4) void attn_fwd(
    const bf16* __restrict__ qkv, const bf16* __restrict__ vtb, bf16* __restrict__ out) {
  __shared__ __align__(16) unsigned char lds[40960];
  unsigned char* Ks = lds;
  unsigned char* Vs = lds + 16384;
  unsigned char* Ps = lds + 32768;
  const int tid = threadIdx.x, lane = tid & 63, w = tid >> 6;
  const int hi = lane >> 4, lo = lane & 15;
  const int qt = blockIdx.x, bh = blockIdx.y;
  const int b = bh >> 4, h = bh & 15, g = h >> 2;
  const size_t tok0 = (size_t)b * 1024;
  const int q0 = qt * 64;

  bf16x8 qf[4];
  {
    const bf16* qp = qkv + (tok0 + q0 + w * 16 + lo) * 3072 + h * 128 + hi * 8;
#pragma unroll
    for (int kc = 0; kc < 4; ++kc) qf[kc] = *(const bf16x8*)(qp + kc * 32);
  }

  float m2 = -1e30f, lsum = 0.f;
  f32x4 oacc[8] = {};
  const float c2 = 0.08838834764831845f * 1.44269504088896f;

  const int o = tid * 16;
  const bf16* kbase = qkv + tok0 * 3072 + 2048 + g * 128;
  const bf16* vbase = vtb + (size_t)(b * 4 + g) * 128 * 1024;
  unsigned char* Pw = Ps + w * 2048;

  for (int t = 0; t < 16; ++t) {
    const int kb = t * 64;
#pragma unroll
    for (int rd = 0; rd < 4; ++rd) {
      const int oo = o + rd * 4096;
      const int rK = oo >> 8, cK = ((oo >> 4) & 15) ^ (rK & 15);
      const int rV = oo >> 7, cV = ((oo >> 4) & 7) ^ (rV & 7);
      async16(Ks + oo, kbase + (size_t)(kb + rK) * 3072 + cK * 8);
      async16(Vs + oo, vbase + (size_t)rV * 1024 + kb + cV * 8);
    }
    __syncthreads();

    f32x4 sc[4] = {};
#pragma unroll
    for (int kc = 0; kc < 4; ++kc) {
#pragma unroll
      for (int kg = 0; kg < 4; ++kg) {
        const int row = kg * 16 + lo;
        bf16x8 kf = *(const bf16x8*)(Ks + row * 256 + ((((kc << 2) + hi) ^ (row & 15)) << 4));
        sc[kg] = MFMA16(kf, qf[kc], sc[kg]);
      }
    }

    float mx = sc[0][0];
#pragma unroll
    for (int kg = 0; kg < 4; ++kg)
#pragma unroll
      for (int r = 0; r < 4; ++r) mx = fmaxf(mx, sc[kg][r]);
    mx = fmaxf(mx, __shfl_xor(mx, 16));
    mx = fmaxf(mx, __shfl_xor(mx, 32));
    mx *= c2;
    const float mn = fmaxf(m2, mx);
    const float corr = fexp2(m2 - mn);
    m2 = mn;

    float rs = 0.f;
#pragma unroll
    for (int kg = 0; kg < 4; ++kg) {
      union { bf16 hh[4]; uint2 v; } pk;
#pragma unroll
      for (int r = 0; r < 4; ++r) {
        const float p = fexp2(sc[kg][r] * c2 - mn);
        rs += p;
        pk.hh[r] = __float2bfloat16(p);
      }
      *(uint2*)(Pw + lo * 128 + ((((kg << 1) + (hi >> 1)) ^ (lo & 7)) << 4) +
                ((hi & 1) << 3)) = pk.v;
    }
    rs += __shfl_xor(rs, 16);
    rs += __shfl_xor(rs, 32);
    lsum = lsum * corr + rs;

    float corr_r[4];
#pragma unroll
    for (int r = 0; r < 4; ++r) corr_r[r] = __shfl(corr, hi * 4 + r);
#pragma unroll
    for (int dg = 0; dg < 8; ++dg)
#pragma unroll
      for (int r = 0; r < 4; ++r) oacc[dg][r] *= corr_r[r];

    asm volatile("s_waitcnt lgkmcnt(0)" ::: "memory");

    bf16x8 pf[2];
#pragma unroll
    for (int kc = 0; kc < 2; ++kc)
      pf[kc] = *(const bf16x8*)(Pw + lo * 128 + ((((kc << 2) + hi) ^ (lo & 7)) << 4));
#pragma unroll
    for (int dg = 0; dg < 8; ++dg) {
#pragma unroll
      for (int kc = 0; kc < 2; ++kc) {
        const int vrow = dg * 16 + lo;
        bf16x8 vf = *(const bf16x8*)(Vs + vrow * 128 + ((((kc << 2) + hi) ^ (vrow & 7)) << 4));
        oacc[dg] = MFMA16(pf[kc], vf, oacc[dg]);
      }
    }
    __syncthreads();
  }

  const float linv = 1.0f / lsum;
  float lr[4];
#pragma unroll
  for (int r = 0; r < 4; ++r) lr[r] = __shfl(linv, hi * 4 + r);
  bf16* op = out + (tok0 + q0 + w * 16 + hi * 4) * 2048 + h * 128 + lo;
#pragma unroll
  for (int dg = 0; dg < 8; ++dg)
#pragma unroll
    for (int r = 0; r < 4; ++r)
      op[(size_t)r * 2048 + dg * 16] = __float2bfloat16(oacc[dg][r] * lr[r]);
}

// ------------------------------------------------------------------ launch ----
extern "C" void kernel_launch(void* const* d_in, const int* in_sizes, int n_in,
                              void* d_out, int out_size, void* d_ws, size_t ws_size,
                              hipStream_t stream) {
  (void)in_sizes; (void)n_in; (void)out_size; (void)ws_size;
  const float* x  = (const float*)d_in[0];
  const float* s1 = (const float*)d_in[1];
  const float* Wq = (const float*)d_in[2];
  const float* bq = (const float*)d_in[3];
  const float* Wk = (const float*)d_in[4];
  const float* bk = (const float*)d_in[5];
  const float* Wv = (const float*)d_in[6];
  const float* bv = (const float*)d_in[7];
  const float* Wo = (const float*)d_in[8];
  const float* bo = (const float*)d_in[9];
  const float* W1 = (const float*)d_in[10];
  const float* b1 = (const float*)d_in[11];
  const float* W2 = (const float*)d_in[12];
  const float* b2 = (const float*)d_in[13];
  float* outp = (float*)d_out;

  char* ws = (char*)d_ws;
  bf16*  xn    = (bf16*)(ws + 0);            // 16.78 MB [4096][2048]; dead after gemm_p<0>
  bf16*  vtb   = (bf16*)(ws + 0);            // 4.19 MB, aliases dead xn
  bf16*  wcatT = (bf16*)(ws + 16777216);     // 20.97 MB [5120][2048]; dead after gemm_p<0>
  bf16*  attnb = (bf16*)(ws + 16777216);     // 16.78 MB, aliases dead wcatT
  float* bcat  = (float*)(ws + 37748736);    // 20 KB
  bf16*  woT   = (bf16*)(ws + 37769216);     // 8.39 MB
  bf16*  w2T   = (bf16*)(ws + 46157824);     // 8.39 MB
  bf16*  qkvb  = (bf16*)(ws + 54546432);     // 25.17 MB [4096][3072]
  bf16*  gbuf  = (bf16*)(ws + 79712256);     // 16.78 MB [4096][2048]
  float* x1    = outp;                       // residual mid lives in d_out

  const dim3 b32x8(32, 8);
  rmsnorm_cast_k<<<dim3(4096), dim3(256), 0, stream>>>(x, s1, xn);
  concat_bias_k<<<dim3(20), dim3(256), 0, stream>>>(bq, bk, bv, b1, bcat);
  transpose_cast_k<<<dim3(64, 64), b32x8, 0, stream>>>(Wq, wcatT, 2048, 0);
  transpose_cast_k<<<dim3(16, 64), b32x8, 0, stream>>>(Wk, wcatT, 512, 2048);
  transpose_cast_k<<<dim3(16, 64), b32x8, 0, stream>>>(Wv, wcatT, 512, 2560);
  transpose_cast_k<<<dim3(64, 64), b32x8, 0, stream>>>(W1, wcatT, 2048, 3072);
  transpose_cast_k<<<dim3(64, 64), b32x8, 0, stream>>>(Wo, woT, 2048, 0);
  transpose_cast_k<<<dim3(64, 64), b32x8, 0, stream>>>(W2, w2T, 2048, 0);
  // merged QKV + W1 projection: [4096,2048] x [2048,5120]
  gemm_p<0><<<dim3(16, 40), dim3(512), 0, stream>>>(xn, wcatT, bcat, (const float*)nullptr,
                                                    (void*)qkvb, (void*)gbuf, 2048);
  transpose_v_k<<<dim3(32, 4, 16), b32x8, 0, stream>>>(qkvb, vtb);
  attn_fwd<<<dim3(16, 64), dim3(256), 0, stream>>>(qkvb, vtb, attnb);
  // x1 = x + attn @ Wo + bo
  gemm_p<1><<<dim3(16, 16), dim3(512), 0, stream>>>(attnb, woT, bo, x, (void*)x1,
                                                    (void*)nullptr, 2048);
  // out = x1 + g @ W2 + b2
  gemm_p<1><<<dim3(16, 16), dim3(512), 0, stream>>>(gbuf, w2T, b2, x1, (void*)outp,
                                                    (void*)nullptr, 2048);
}

// Round 4
// 284.414 us; speedup vs baseline: 1.0905x; 1.0905x over previous
//
#include <hip/hip_runtime.h>
#include <hip/hip_bf16.h>
#include <cstdint>

using bf16 = __hip_bfloat16;
typedef __attribute__((ext_vector_type(8))) __bf16 bf16x8;
typedef __attribute__((ext_vector_type(4))) float f32x4;

#define MFMA16(a, b, c) __builtin_amdgcn_mfma_f32_16x16x32_bf16((a), (b), (c), 0, 0, 0)

#if __has_builtin(__builtin_amdgcn_exp2f)
__device__ __forceinline__ float fexp2(float x) { return __builtin_amdgcn_exp2f(x); }
#else
__device__ __forceinline__ float fexp2(float x) { return exp2f(x); }
#endif

// Async global->LDS 16B copy. LDS dest must be wave-uniform base + lane*16.
__device__ __forceinline__ void async16(void* lds_ptr, const void* gptr) {
  auto g = reinterpret_cast<__attribute__((address_space(1))) unsigned int*>(
      reinterpret_cast<uintptr_t>(gptr));
  auto l = reinterpret_cast<__attribute__((address_space(3))) unsigned int*>(
      static_cast<unsigned int>(reinterpret_cast<uintptr_t>(lds_ptr)));
  __builtin_amdgcn_global_load_lds(g, l, 16, 0, 0);
}

// ---------------------------------------------------------------- RMSNorm ----
__global__ __launch_bounds__(256) void rmsnorm_cast_k(
    const float* __restrict__ x, const float* __restrict__ sc, bf16* __restrict__ xn) {
  const int row = blockIdx.x, tid = threadIdx.x;
  const float4* xr = (const float4*)(x + (size_t)row * 2048);
  float4 a = xr[tid * 2], b = xr[tid * 2 + 1];
  float ss = a.x * a.x + a.y * a.y + a.z * a.z + a.w * a.w +
             b.x * b.x + b.y * b.y + b.z * b.z + b.w * b.w;
#pragma unroll
  for (int d = 1; d < 64; d <<= 1) ss += __shfl_xor(ss, d);
  __shared__ float sm[4];
  if ((tid & 63) == 0) sm[tid >> 6] = ss;
  __syncthreads();
  const float rinv = rsqrtf((sm[0] + sm[1] + sm[2] + sm[3]) * (1.0f / 2048.0f) + 1e-6f);
  const float4* sp = (const float4*)sc;
  float4 s0 = sp[tid * 2], s1 = sp[tid * 2 + 1];
  union { bf16 h[8]; bf16x8 v; } o;
  o.h[0] = __float2bfloat16(a.x * rinv * s0.x);
  o.h[1] = __float2bfloat16(a.y * rinv * s0.y);
  o.h[2] = __float2bfloat16(a.z * rinv * s0.z);
  o.h[3] = __float2bfloat16(a.w * rinv * s0.w);
  o.h[4] = __float2bfloat16(b.x * rinv * s1.x);
  o.h[5] = __float2bfloat16(b.y * rinv * s1.y);
  o.h[6] = __float2bfloat16(b.z * rinv * s1.z);
  o.h[7] = __float2bfloat16(b.w * rinv * s1.w);
  *(bf16x8*)(xn + (size_t)row * 2048 + tid * 8) = o.v;
}

// ------------------------------------------------- weight transpose + cast ----
__global__ void transpose_cast_k(const float* __restrict__ W, bf16* __restrict__ Wt,
                                 int N, int row_off) {
  __shared__ float t[32][33];
  const int n0 = blockIdx.x * 32, k0 = blockIdx.y * 32;
  const int tx = threadIdx.x, ty = threadIdx.y;
#pragma unroll
  for (int i = 0; i < 4; ++i)
    t[ty + 8 * i][tx] = W[(size_t)(k0 + ty + 8 * i) * N + n0 + tx];
  __syncthreads();
#pragma unroll
  for (int i = 0; i < 4; ++i)
    Wt[(size_t)(row_off + n0 + ty + 8 * i) * 2048 + k0 + tx] =
        __float2bfloat16(t[tx][ty + 8 * i]);
}

// V slice of QKV [4096][3072] (cols 2560..3071) -> Vt bf16 [16][128][1024]
__global__ void transpose_v_k(const bf16* __restrict__ qkv, bf16* __restrict__ vtb) {
  __shared__ bf16 t[32][33];
  const int bh = blockIdx.z, b = bh >> 2, g = bh & 3;
  const int s0 = blockIdx.x * 32, d0 = blockIdx.y * 32;
  const int tx = threadIdx.x, ty = threadIdx.y;
#pragma unroll
  for (int i = 0; i < 4; ++i)
    t[ty + 8 * i][tx] =
        qkv[(size_t)(b * 1024 + s0 + ty + 8 * i) * 3072 + 2560 + g * 128 + d0 + tx];
  __syncthreads();
#pragma unroll
  for (int i = 0; i < 4; ++i)
    vtb[((size_t)bh * 128 + d0 + ty + 8 * i) * 1024 + s0 + tx] = t[tx][ty + 8 * i];
}

__global__ void concat_bias_k(const float* __restrict__ bq, const float* __restrict__ bk,
                              const float* __restrict__ bv, const float* __restrict__ b1,
                              float* __restrict__ o) {
  const int i = blockIdx.x * 256 + threadIdx.x;
  if (i < 2048) o[i] = bq[i];
  else if (i < 2560) o[i] = bk[i - 2048];
  else if (i < 3072) o[i] = bv[i - 2560];
  else o[i] = b1[i - 3072];
}

// --------------------------------------------- ring-pipelined GEMM (T3/T4) ----
// C[M][N] = A[M][K] @ Bt[N][K]^T. Tile 128x128, BK=64 processed as two 32-K
// halves. LDS = ring of 4 half-slots per matrix (A: 4x8KB @0, B: 4x8KB @32KB)
// = 64KB -> 2 blocks/CU. Each phase: 8 ds_read_b128 + stage half h+3 (4
// global_load_lds) + counted vmcnt(8) + barrier + 16 MFMA (setprio) + barrier.
// Slot reuse race-free: reads of slot s complete (auto-lgkm before MFMA) two
// barriers before the overwriting stage of s+4 is issued.
#define GR_PHASE(HH, DO_STAGE, VMW)                                                \
  {                                                                                \
    const int sa = ((HH) & 3) * 8192, sb = 32768 + sa;                             \
    bf16x8 af[4], bf_[4];                                                          \
    _Pragma("unroll") for (int mi = 0; mi < 4; ++mi) {                             \
      const int R = (w >> 1) * 64 + mi * 16 + lo;                                  \
      af[mi] = *(const bf16x8*)(lds + sa + R * 64 + ((hi ^ ((R >> 1) & 3)) << 4)); \
    }                                                                              \
    _Pragma("unroll") for (int nj = 0; nj < 4; ++nj) {                             \
      const int S = (w & 1) * 64 + nj * 16 + lo;                                   \
      bf_[nj] = *(const bf16x8*)(lds + sb + S * 64 + ((hi ^ ((S >> 1) & 3)) << 4)); \
    }                                                                              \
    DO_STAGE;                                                                      \
    asm volatile("s_waitcnt vmcnt(" #VMW ")" ::: "memory");                        \
    __builtin_amdgcn_sched_barrier(0);                                             \
    __builtin_amdgcn_s_barrier();                                                  \
    asm volatile("" ::: "memory");                                                 \
    __builtin_amdgcn_s_setprio(1);                                                 \
    _Pragma("unroll") for (int mi = 0; mi < 4; ++mi)                               \
      _Pragma("unroll") for (int nj = 0; nj < 4; ++nj)                             \
        acc[mi][nj] = MFMA16(af[mi], bf_[nj], acc[mi][nj]);                        \
    __builtin_amdgcn_s_setprio(0);                                                 \
    asm volatile("" ::: "memory");                                                 \
    __builtin_amdgcn_s_barrier();                                                  \
    asm volatile("" ::: "memory");                                                 \
  }

template <int EPI>
__global__ __launch_bounds__(256, 2) void gemm_r(
    const bf16* __restrict__ A, const bf16* __restrict__ Bt,
    const float* __restrict__ bias, const float* __restrict__ res,
    void* __restrict__ out0, void* __restrict__ out1, int K) {
  __shared__ __align__(16) unsigned char lds[65536];
  const int tid = threadIdx.x, lane = tid & 63, w = tid >> 6;
  const int hi = lane >> 4, lo = lane & 15;
  const int brow = blockIdx.x * 128, bcol = blockIdx.y * 128;
  const int nt = K >> 6;  // 64-K tiles; halves H = 2*nt

  // staging coords: half-slot is [128 rows][64B]; thread covers bytes o0, o1.
  const int o0 = tid * 16, o1 = o0 + 4096;
  const int r0 = o0 >> 6, c0 = ((((o0 >> 4) & 3) ^ ((r0 >> 1) & 3)) << 3);
  const int r1 = o1 >> 6, c1 = ((((o1 >> 4) & 3) ^ ((r1 >> 1) & 3)) << 3);
  const bf16* gA0 = A + (size_t)(brow + r0) * K + c0;
  const bf16* gA1 = A + (size_t)(brow + r1) * K + c1;
  const bf16* gB0 = Bt + (size_t)(bcol + r0) * K + c0;
  const bf16* gB1 = Bt + (size_t)(bcol + r1) * K + c1;

  auto stg = [&](int h) {
    const int s = (h & 3) * 8192;
    const int kb = h * 32;
    async16(lds + s + o0, gA0 + kb);
    async16(lds + s + o1, gA1 + kb);
    async16(lds + 32768 + s + o0, gB0 + kb);
    async16(lds + 32768 + s + o1, gB1 + kb);
  };

  stg(0); stg(1); stg(2);  // 12 loads in flight
  asm volatile("s_waitcnt vmcnt(8)" ::: "memory");  // half 0 landed
  __builtin_amdgcn_sched_barrier(0);
  __builtin_amdgcn_s_barrier();
  asm volatile("" ::: "memory");

  f32x4 acc[4][4] = {};
  int t = 0;
  for (; t < nt - 2; ++t) {
    GR_PHASE(2 * t,     stg(2 * t + 3), 8);
    GR_PHASE(2 * t + 1, stg(2 * t + 4), 8);
  }
  // t = nt-2: stage last half (H-1), then taper vmcnt 8 -> 4 -> 0
  GR_PHASE(2 * t,     stg(2 * t + 3), 8);
  GR_PHASE(2 * t + 1, (void)0, 4);
  ++t;
  GR_PHASE(2 * t,     (void)0, 0);
  GR_PHASE(2 * t + 1, (void)0, 0);

#pragma unroll
  for (int nj = 0; nj < 4; ++nj) {
    const int col = bcol + (w & 1) * 64 + nj * 16 + lo;
    const float bs = bias[col];
#pragma unroll
    for (int mi = 0; mi < 4; ++mi) {
      const int row0 = brow + (w >> 1) * 64 + mi * 16 + hi * 4;
#pragma unroll
      for (int r = 0; r < 4; ++r) {
        float v = acc[mi][nj][r] + bs;
        const int row = row0 + r;
        if (EPI == 0) {
          if (bcol < 3072) {
            ((bf16*)out0)[(size_t)row * 3072 + col] = __float2bfloat16(v);
          } else {
            const float sg = 1.0f / (1.0f + __expf(-v));
            v = v * sg * v;
            ((bf16*)out1)[(size_t)row * 2048 + (col - 3072)] = __float2bfloat16(v);
          }
        } else {
          v += res[(size_t)row * 2048 + col];
          ((float*)out0)[(size_t)row * 2048 + col] = v;
        }
      }
    }
  }
}

// --------------------------------------------------------------- attention ----
__global__ __launch_bounds__(256, 4) void attn_fwd(
    const bf16* __restrict__ qkv, const bf16* __restrict__ vtb, bf16* __restrict__ out) {
  __shared__ __align__(16) unsigned char lds[40960];
  unsigned char* Ks = lds;
  unsigned char* Vs = lds + 16384;
  unsigned char* Ps = lds + 32768;
  const int tid = threadIdx.x, lane = tid & 63, w = tid >> 6;
  const int hi = lane >> 4, lo = lane & 15;
  const int qt = blockIdx.x, bh = blockIdx.y;
  const int b = bh >> 4, h = bh & 15, g = h >> 2;
  const size_t tok0 = (size_t)b * 1024;
  const int q0 = qt * 64;

  bf16x8 qf[4];
  {
    const bf16* qp = qkv + (tok0 + q0 + w * 16 + lo) * 3072 + h * 128 + hi * 8;
#pragma unroll
    for (int kc = 0; kc < 4; ++kc) qf[kc] = *(const bf16x8*)(qp + kc * 32);
  }

  float m2 = -1e30f, lsum = 0.f;
  f32x4 oacc[8] = {};
  const float c2 = 0.08838834764831845f * 1.44269504088896f;

  const int o = tid * 16;
  const bf16* kbase = qkv + tok0 * 3072 + 2048 + g * 128;
  const bf16* vbase = vtb + (size_t)(b * 4 + g) * 128 * 1024;
  unsigned char* Pw = Ps + w * 2048;

  for (int t = 0; t < 16; ++t) {
    const int kb = t * 64;
#pragma unroll
    for (int rd = 0; rd < 4; ++rd) {
      const int oo = o + rd * 4096;
      const int rK = oo >> 8, cK = ((oo >> 4) & 15) ^ (rK & 15);
      const int rV = oo >> 7, cV = ((oo >> 4) & 7) ^ (rV & 7);
      async16(Ks + oo, kbase + (size_t)(kb + rK) * 3072 + cK * 8);
      async16(Vs + oo, vbase + (size_t)rV * 1024 + kb + cV * 8);
    }
    __syncthreads();

    f32x4 sc[4] = {};
#pragma unroll
    for (int kc = 0; kc < 4; ++kc) {
#pragma unroll
      for (int kg = 0; kg < 4; ++kg) {
        const int row = kg * 16 + lo;
        bf16x8 kf = *(const bf16x8*)(Ks + row * 256 + ((((kc << 2) + hi) ^ (row & 15)) << 4));
        sc[kg] = MFMA16(kf, qf[kc], sc[kg]);
      }
    }

    float mx = sc[0][0];
#pragma unroll
    for (int kg = 0; kg < 4; ++kg)
#pragma unroll
      for (int r = 0; r < 4; ++r) mx = fmaxf(mx, sc[kg][r]);
    mx = fmaxf(mx, __shfl_xor(mx, 16));
    mx = fmaxf(mx, __shfl_xor(mx, 32));
    mx *= c2;
    const float mn = fmaxf(m2, mx);
    const float corr = fexp2(m2 - mn);
    m2 = mn;

    float rs = 0.f;
#pragma unroll
    for (int kg = 0; kg < 4; ++kg) {
      union { bf16 hh[4]; uint2 v; } pk;
#pragma unroll
      for (int r = 0; r < 4; ++r) {
        const float p = fexp2(sc[kg][r] * c2 - mn);
        rs += p;
        pk.hh[r] = __float2bfloat16(p);
      }
      *(uint2*)(Pw + lo * 128 + ((((kg << 1) + (hi >> 1)) ^ (lo & 7)) << 4) +
                ((hi & 1) << 3)) = pk.v;
    }
    rs += __shfl_xor(rs, 16);
    rs += __shfl_xor(rs, 32);
    lsum = lsum * corr + rs;

    float corr_r[4];
#pragma unroll
    for (int r = 0; r < 4; ++r) corr_r[r] = __shfl(corr, hi * 4 + r);
#pragma unroll
    for (int dg = 0; dg < 8; ++dg)
#pragma unroll
      for (int r = 0; r < 4; ++r) oacc[dg][r] *= corr_r[r];

    asm volatile("s_waitcnt lgkmcnt(0)" ::: "memory");

    bf16x8 pf[2];
#pragma unroll
    for (int kc = 0; kc < 2; ++kc)
      pf[kc] = *(const bf16x8*)(Pw + lo * 128 + ((((kc << 2) + hi) ^ (lo & 7)) << 4));
#pragma unroll
    for (int dg = 0; dg < 8; ++dg) {
#pragma unroll
      for (int kc = 0; kc < 2; ++kc) {
        const int vrow = dg * 16 + lo;
        bf16x8 vf = *(const bf16x8*)(Vs + vrow * 128 + ((((kc << 2) + hi) ^ (vrow & 7)) << 4));
        oacc[dg] = MFMA16(pf[kc], vf, oacc[dg]);
      }
    }
    __syncthreads();
  }

  const float linv = 1.0f / lsum;
  float lr[4];
#pragma unroll
  for (int r = 0; r < 4; ++r) lr[r] = __shfl(linv, hi * 4 + r);
  bf16* op = out + (tok0 + q0 + w * 16 + hi * 4) * 2048 + h * 128 + lo;
#pragma unroll
  for (int dg = 0; dg < 8; ++dg)
#pragma unroll
    for (int r = 0; r < 4; ++r)
      op[(size_t)r * 2048 + dg * 16] = __float2bfloat16(oacc[dg][r] * lr[r]);
}

// ------------------------------------------------------------------ launch ----
extern "C" void kernel_launch(void* const* d_in, const int* in_sizes, int n_in,
                              void* d_out, int out_size, void* d_ws, size_t ws_size,
                              hipStream_t stream) {
  (void)in_sizes; (void)n_in; (void)out_size; (void)ws_size;
  const float* x  = (const float*)d_in[0];
  const float* s1 = (const float*)d_in[1];
  const float* Wq = (const float*)d_in[2];
  const float* bq = (const float*)d_in[3];
  const float* Wk = (const float*)d_in[4];
  const float* bk = (const float*)d_in[5];
  const float* Wv = (const float*)d_in[6];
  const float* bv = (const float*)d_in[7];
  const float* Wo = (const float*)d_in[8];
  const float* bo = (const float*)d_in[9];
  const float* W1 = (const float*)d_in[10];
  const float* b1 = (const float*)d_in[11];
  const float* W2 = (const float*)d_in[12];
  const float* b2 = (const float*)d_in[13];
  float* outp = (float*)d_out;

  char* ws = (char*)d_ws;
  bf16*  xn    = (bf16*)(ws + 0);            // 16.78 MB [4096][2048]; dead after gemm_r<0>
  bf16*  vtb   = (bf16*)(ws + 0);            // 4.19 MB, aliases dead xn
  bf16*  wcatT = (bf16*)(ws + 16777216);     // 20.97 MB [5120][2048]; dead after gemm_r<0>
  bf16*  attnb = (bf16*)(ws + 16777216);     // 16.78 MB, aliases dead wcatT
  float* bcat  = (float*)(ws + 37748736);    // 20 KB
  bf16*  woT   = (bf16*)(ws + 37769216);     // 8.39 MB
  bf16*  w2T   = (bf16*)(ws + 46157824);     // 8.39 MB
  bf16*  qkvb  = (bf16*)(ws + 54546432);     // 25.17 MB [4096][3072]
  bf16*  gbuf  = (bf16*)(ws + 79712256);     // 16.78 MB [4096][2048]
  float* x1    = outp;                       // residual mid lives in d_out

  const dim3 b32x8(32, 8);
  rmsnorm_cast_k<<<dim3(4096), dim3(256), 0, stream>>>(x, s1, xn);
  concat_bias_k<<<dim3(20), dim3(256), 0, stream>>>(bq, bk, bv, b1, bcat);
  transpose_cast_k<<<dim3(64, 64), b32x8, 0, stream>>>(Wq, wcatT, 2048, 0);
  transpose_cast_k<<<dim3(16, 64), b32x8, 0, stream>>>(Wk, wcatT, 512, 2048);
  transpose_cast_k<<<dim3(16, 64), b32x8, 0, stream>>>(Wv, wcatT, 512, 2560);
  transpose_cast_k<<<dim3(64, 64), b32x8, 0, stream>>>(W1, wcatT, 2048, 3072);
  transpose_cast_k<<<dim3(64, 64), b32x8, 0, stream>>>(Wo, woT, 2048, 0);
  transpose_cast_k<<<dim3(64, 64), b32x8, 0, stream>>>(W2, w2T, 2048, 0);
  // merged QKV + W1 projection: [4096,2048] x [2048,5120], 1280 blocks
  gemm_r<0><<<dim3(32, 40), dim3(256), 0, stream>>>(xn, wcatT, bcat, (const float*)nullptr,
                                                    (void*)qkvb, (void*)gbuf, 2048);
  transpose_v_k<<<dim3(32, 4, 16), b32x8, 0, stream>>>(qkvb, vtb);
  attn_fwd<<<dim3(16, 64), dim3(256), 0, stream>>>(qkvb, vtb, attnb);
  // x1 = x + attn @ Wo + bo
  gemm_r<1><<<dim3(32, 16), dim3(256), 0, stream>>>(attnb, woT, bo, x, (void*)x1,
                                                    (void*)nullptr, 2048);
  // out = x1 + g @ W2 + b2
  gemm_r<1><<<dim3(32, 16), dim3(256), 0, stream>>>(gbuf, w2T, b2, x1, (void*)outp,
                                                    (void*)nullptr, 2048);
}